// Round 2
// baseline (649.670 us; speedup 1.0000x reference)
//
#include <hip/hip_runtime.h>
#include <stdint.h>

#define TOKENS 4096
#define HS 1024
#define FFN 4096
#define NE 8
#define CAP 512

typedef __attribute__((ext_vector_type(8))) __bf16 v8bf;
typedef __attribute__((ext_vector_type(4))) float v4f;
typedef __attribute__((ext_vector_type(8))) unsigned short v8us;

typedef __attribute__((address_space(1))) void AS1void;
typedef __attribute__((address_space(1))) const void AS1cvoid;
typedef __attribute__((address_space(3))) void AS3void;

// round-to-nearest-even fp32 -> bf16 bits
__device__ __forceinline__ unsigned short f2bf(float f) {
    union { float f; unsigned int u; } c; c.f = f;
    unsigned int u = c.u;
    unsigned int r = (u + 0x7fffu + ((u >> 16) & 1u)) >> 16;
    return (unsigned short)r;
}

// async global->LDS, 16B per lane. LDS dest must be wave-uniform base; HW adds lane*16.
__device__ __forceinline__ void gload16(const void* g, void* l) {
    __builtin_amdgcn_global_load_lds((AS1cvoid*)g, (AS3void*)l, 16, 0, 0);
}

// exact tanh via hardware exp: tanh(u) = sign(u) * (1 - e^{-2|u|}) / (1 + e^{-2|u|})
__device__ __forceinline__ float fast_tanh(float u) {
    float a = __expf(-2.f * fabsf(u));
    float t = (1.f - a) / (1.f + a);
    return copysignf(t, u);
}

// ---------------------------------------------------------------- cvt x -> bf16
__global__ void cvt_x_kernel(const float* __restrict__ x, unsigned short* __restrict__ xb) {
    size_t i = (size_t)blockIdx.x * 256 + threadIdx.x;   // 524288 threads, 8 floats each
    const float4* xv = (const float4*)x;
    float4 a = xv[i * 2];
    float4 b = xv[i * 2 + 1];
    v8us r;
    r[0] = f2bf(a.x); r[1] = f2bf(a.y); r[2] = f2bf(a.z); r[3] = f2bf(a.w);
    r[4] = f2bf(b.x); r[5] = f2bf(b.y); r[6] = f2bf(b.z); r[7] = f2bf(b.w);
    *(v8us*)(xb + i * 8) = r;
}

// ------------------------------------------- transpose + convert weights -> bf16
// in: [E][rows][cols] fp32 -> out: [E][cols][rows] bf16.  64x64 tiles, block=256.
// loads: float4 coalesced (256B/16 lanes); stores: v8us 16B/lane (64B contiguous per 4 lanes)
__global__ void transpose_cvt_kernel(const float* __restrict__ in,
                                     unsigned short* __restrict__ outp,
                                     int rows, int cols) {
    __shared__ float tile[64][65];
    const size_t esz = (size_t)rows * cols;
    const float* ine = in + (size_t)blockIdx.z * esz;
    unsigned short* oute = outp + (size_t)blockIdx.z * esz;
    int c0 = blockIdx.x * 64, r0 = blockIdx.y * 64;
    int t = threadIdx.x;
    int lc = (t & 15) * 4;      // col offset in tile (float4)
    int lr = t >> 4;            // 0..15
#pragma unroll
    for (int i = 0; i < 4; ++i) {
        int r = lr + 16 * i;
        float4 v = *(const float4*)&ine[(size_t)(r0 + r) * cols + c0 + lc];
        tile[r][lc] = v.x; tile[r][lc + 1] = v.y; tile[r][lc + 2] = v.z; tile[r][lc + 3] = v.w;
    }
    __syncthreads();
    int oc = t >> 2;            // 0..63 output row (= input col)
    int rc = (t & 3) * 8;       // row chunk base
#pragma unroll
    for (int i = 0; i < 2; ++i) {
        int rb = rc + 32 * i;
        v8us v;
#pragma unroll
        for (int j = 0; j < 8; ++j) v[j] = f2bf(tile[rb + j][oc]);
        *(v8us*)&oute[(size_t)(c0 + oc) * rows + r0 + rb] = v;
    }
}

// ---------------------------------------------------------------- router top-2
__global__ void router_kernel(const float* __restrict__ x, const float* __restrict__ rw,
                              int* __restrict__ topk_e, float* __restrict__ topk_w) {
    __shared__ float rwT[NE * HS];   // rwT[e][hs]
    int tid = threadIdx.x;           // 256
    for (int i = tid; i < NE * HS; i += 256)
        rwT[(i & 7) * HS + (i >> 3)] = rw[i];
    __syncthreads();
    int lane = tid & 63, wave = tid >> 6;
    int t = blockIdx.x * 4 + wave;
    const float* xr = x + (size_t)t * HS;
    float acc[NE] = {0.f, 0.f, 0.f, 0.f, 0.f, 0.f, 0.f, 0.f};
#pragma unroll
    for (int it = 0; it < 16; ++it) {
        float xv = xr[lane + 64 * it];
#pragma unroll
        for (int e = 0; e < NE; ++e) acc[e] += xv * rwT[e * HS + lane + 64 * it];
    }
#pragma unroll
    for (int e = 0; e < NE; ++e) {
#pragma unroll
        for (int off = 32; off > 0; off >>= 1)
            acc[e] += __shfl_down(acc[e], off, 64);
    }
    if (lane == 0) {
        int b1 = 0; float v1 = acc[0];
#pragma unroll
        for (int e = 1; e < NE; ++e) if (acc[e] > v1) { v1 = acc[e]; b1 = e; }
        int b2 = -1; float v2 = -3.4e38f;
#pragma unroll
        for (int e = 0; e < NE; ++e)
            if (e != b1 && acc[e] > v2) { v2 = acc[e]; b2 = e; }
        float s = 0.f;
#pragma unroll
        for (int e = 0; e < NE; ++e) s += expf(acc[e] - v1);
        float inv = 1.f / s;
        topk_e[t * 2] = b1;
        topk_e[t * 2 + 1] = b2;
        topk_w[t * 2] = inv;                 // exp(v1-v1)/s
        topk_w[t * 2 + 1] = expf(v2 - v1) * inv;
    }
}

// ------------------------------------------------- dispatch: stable capped lists
__global__ void dispatch_kernel(const int* __restrict__ topk_e,
                                const float* __restrict__ topk_w,
                                int* __restrict__ comb_tok,
                                float* __restrict__ comb_gate) {
    __shared__ int hist[1024 * 8];
    __shared__ int c0[NE];
    __shared__ int tpe_s[NE];
    const int tid = threadIdx.x;   // 1024
    for (int i = tid; i < NE * 1024; i += 1024) { comb_tok[i] = 0; comb_gate[i] = 0.f; }

    for (int k = 0; k < 2; ++k) {
        int cnt[NE];
#pragma unroll
        for (int e = 0; e < NE; ++e) cnt[e] = 0;
        int myexp[4];
#pragma unroll
        for (int j = 0; j < 4; ++j) {
            int t = tid * 4 + j;
            int ex = topk_e[t * 2 + k];
            myexp[j] = ex;
            cnt[ex]++;
        }
#pragma unroll
        for (int e = 0; e < NE; ++e) hist[tid * 8 + e] = cnt[e];
        __syncthreads();
        for (int off = 1; off < 1024; off <<= 1) {
            int v[NE];
#pragma unroll
            for (int e = 0; e < NE; ++e) {
                v[e] = hist[tid * 8 + e];
                if (tid >= off) v[e] += hist[(tid - off) * 8 + e];
            }
            __syncthreads();
#pragma unroll
            for (int e = 0; e < NE; ++e) hist[tid * 8 + e] = v[e];
            __syncthreads();
        }
        int base[NE];
#pragma unroll
        for (int e = 0; e < NE; ++e) base[e] = hist[tid * 8 + e] - cnt[e];
        if (tid == 1023) {
#pragma unroll
            for (int e = 0; e < NE; ++e) tpe_s[e] = hist[1023 * 8 + e];
        }
        __syncthreads();
        if (k == 0 && tid < NE) c0[tid] = min(tpe_s[tid], CAP);
        __syncthreads();
#pragma unroll
        for (int j = 0; j < 4; ++j) {
            int t = tid * 4 + j;
            int ex = myexp[j];
            int p = base[ex]++;
            if (p < CAP) {
                int idx = (k == 0) ? p : (c0[ex] + p);
                comb_tok[ex * 1024 + idx] = t;
                comb_gate[ex * 1024 + idx] = topk_w[t * 2 + k];
            }
        }
        __syncthreads();
    }
}

// ---------------------------------------------------------------- out = bias
__global__ void init_out_kernel(float* __restrict__ out, const float* __restrict__ bias) {
    size_t i = (size_t)blockIdx.x * 256 + threadIdx.x;   // 1M threads, float4 each
    const float4* b4 = (const float4*)bias;
    ((float4*)out)[i] = b4[i & 255];
}

// ------------------------------------------------- GEMM1: h = gelu(gather(x) @ W1e)
// 1D grid 2048: id&7 = expert (XCD-affine), rest: mt 0..7, nt 0..31
__global__ __launch_bounds__(256) void gemm1_kernel(
    const unsigned short* __restrict__ xb,      // [TOKENS][HS] bf16
    const unsigned short* __restrict__ w1t,     // [E][FFN][HS] bf16 (pre-transposed)
    const int* __restrict__ comb_tok,           // [E][1024]
    unsigned short* __restrict__ h)             // [E][1024][FFN] bf16
{
    __shared__ __align__(16) unsigned short As[128 * 32];
    __shared__ __align__(16) unsigned short Bs[128 * 32];
    const int id = blockIdx.x;
    const int e = id & 7;
    const int rest = id >> 3;
    const int mt = rest & 7;
    const int nt = rest >> 3;     // 0..31
    const int tid = threadIdx.x;
    const int lane = tid & 63;
    const int wave = tid >> 6;
    const int seg = lane & 3;
    const int lrow = lane >> 2;

    const int arow0 = wave * 32 + lrow;
    const int arow1 = arow0 + 16;
    const int tok0 = comb_tok[e * 1024 + mt * 128 + arow0];
    const int tok1 = comb_tok[e * 1024 + mt * 128 + arow1];
    const unsigned short* gA0 = xb + (size_t)tok0 * HS + seg * 8;
    const unsigned short* gA1 = xb + (size_t)tok1 * HS + seg * 8;
    const unsigned short* wb = w1t + (size_t)e * FFN * HS;
    const unsigned short* gB0 = wb + (size_t)(nt * 128 + arow0) * HS + seg * 8;
    const unsigned short* gB1 = wb + (size_t)(nt * 128 + arow1) * HS + seg * 8;
    unsigned short* lA0 = As + wave * 1024;
    unsigned short* lA1 = As + wave * 1024 + 512;
    unsigned short* lB0 = Bs + wave * 1024;
    unsigned short* lB1 = Bs + wave * 1024 + 512;

    const int m = lane & 15;
    const int quad = lane >> 4;
    const int wr = wave >> 1;
    const int wc = wave & 1;

    v4f acc[4][4];
#pragma unroll
    for (int i = 0; i < 4; ++i)
#pragma unroll
        for (int j = 0; j < 4; ++j) acc[i][j] = (v4f)(0.f);

    for (int kt = 0; kt < HS / 32; ++kt) {
        const int k0 = kt * 32;
        __syncthreads();
        gload16(gA0 + k0, lA0);
        gload16(gA1 + k0, lA1);
        gload16(gB0 + k0, lB0);
        gload16(gB1 + k0, lB1);
        __syncthreads();
        v8bf a[4], b[4];
#pragma unroll
        for (int i = 0; i < 4; ++i)
            a[i] = *(const v8bf*)&As[(wr * 64 + i * 16 + m) * 32 + quad * 8];
#pragma unroll
        for (int j = 0; j < 4; ++j)
            b[j] = *(const v8bf*)&Bs[(wc * 64 + j * 16 + m) * 32 + quad * 8];
#pragma unroll
        for (int i = 0; i < 4; ++i)
#pragma unroll
            for (int j = 0; j < 4; ++j)
                acc[i][j] = __builtin_amdgcn_mfma_f32_16x16x32_bf16(a[i], b[j], acc[i][j], 0, 0, 0);
    }

    unsigned short* hb = h + (size_t)e * 1024 * FFN;
    const int mbase = mt * 128 + wr * 64;
    const int nbase = nt * 128 + wc * 64 + m;
#pragma unroll
    for (int i = 0; i < 4; ++i) {
#pragma unroll
        for (int j = 0; j < 4; ++j) {
            v4f v = acc[i][j];
#pragma unroll
            for (int r = 0; r < 4; ++r) {
                int row = mbase + i * 16 + quad * 4 + r;
                int col = nbase + j * 16;
                float val = v[r];
                float inner = 0.7978845608028654f * (val + 0.044715f * val * val * val);
                float g = 0.5f * val * (1.f + fast_tanh(inner));
                hb[(size_t)row * FFN + col] = f2bf(g);
            }
        }
    }
}

// ------------------------------------------------- GEMM2: out[tok] += gate * (h @ W2e)
// 1D grid 1024: id&7 = expert (XCD-affine); rest: mt 0..7, nt 0..7, ks 0..1 (split-K)
__global__ __launch_bounds__(256) void gemm2_kernel(
    const unsigned short* __restrict__ h,       // [E][1024][FFN] bf16
    const unsigned short* __restrict__ w2t,     // [E][HS][FFN] bf16 (pre-transposed)
    const int* __restrict__ comb_tok,
    const float* __restrict__ comb_gate,
    float* __restrict__ out)                    // [TOKENS][HS] fp32
{
    __shared__ __align__(16) unsigned short As[128 * 32];
    __shared__ __align__(16) unsigned short Bs[128 * 32];
    const int id = blockIdx.x;
    const int e = id & 7;
    const int rest = id >> 3;
    const int mt = rest & 7;
    const int nt = (rest >> 3) & 7;
    const int ks = rest >> 6;       // 0..1 split-K
    const int tid = threadIdx.x;
    const int lane = tid & 63;
    const int wave = tid >> 6;
    const int seg = lane & 3;
    const int lrow = lane >> 2;

    const int arow0 = wave * 32 + lrow;
    const int arow1 = arow0 + 16;
    const unsigned short* hb = h + (size_t)e * 1024 * FFN;
    const unsigned short* gA0 = hb + (size_t)(mt * 128 + arow0) * FFN + seg * 8;
    const unsigned short* gA1 = hb + (size_t)(mt * 128 + arow1) * FFN + seg * 8;
    const unsigned short* wb = w2t + (size_t)e * HS * FFN;
    const unsigned short* gB0 = wb + (size_t)(nt * 128 + arow0) * FFN + seg * 8;
    const unsigned short* gB1 = wb + (size_t)(nt * 128 + arow1) * FFN + seg * 8;
    unsigned short* lA0 = As + wave * 1024;
    unsigned short* lA1 = As + wave * 1024 + 512;
    unsigned short* lB0 = Bs + wave * 1024;
    unsigned short* lB1 = Bs + wave * 1024 + 512;

    const int m = lane & 15;
    const int quad = lane >> 4;
    const int wr = wave >> 1;
    const int wc = wave & 1;

    v4f acc[4][4];
#pragma unroll
    for (int i = 0; i < 4; ++i)
#pragma unroll
        for (int j = 0; j < 4; ++j) acc[i][j] = (v4f)(0.f);

    const int kt0 = ks * (FFN / 64);            // 64 iters per half
    for (int kt = kt0; kt < kt0 + FFN / 64; ++kt) {
        const int k0 = kt * 32;
        __syncthreads();
        gload16(gA0 + k0, lA0);
        gload16(gA1 + k0, lA1);
        gload16(gB0 + k0, lB0);
        gload16(gB1 + k0, lB1);
        __syncthreads();
        v8bf a[4], b[4];
#pragma unroll
        for (int i = 0; i < 4; ++i)
            a[i] = *(const v8bf*)&As[(wr * 64 + i * 16 + m) * 32 + quad * 8];
#pragma unroll
        for (int j = 0; j < 4; ++j)
            b[j] = *(const v8bf*)&Bs[(wc * 64 + j * 16 + m) * 32 + quad * 8];
#pragma unroll
        for (int i = 0; i < 4; ++i)
#pragma unroll
            for (int j = 0; j < 4; ++j)
                acc[i][j] = __builtin_amdgcn_mfma_f32_16x16x32_bf16(a[i], b[j], acc[i][j], 0, 0, 0);
    }

    const int mbase = mt * 128 + wr * 64;
    const int nglob = nt * 128 + wc * 64 + m;
#pragma unroll
    for (int i = 0; i < 4; ++i) {
        int tok_r[4];
        float gate_r[4];
#pragma unroll
        for (int r = 0; r < 4; ++r) {
            int row = mbase + i * 16 + quad * 4 + r;
            tok_r[r] = comb_tok[e * 1024 + row];
            gate_r[r] = comb_gate[e * 1024 + row];
        }
#pragma unroll
        for (int j = 0; j < 4; ++j) {
            v4f v = acc[i][j];
#pragma unroll
            for (int r = 0; r < 4; ++r) {
                if (gate_r[r] != 0.f)
                    atomicAdd(out + (size_t)tok_r[r] * HS + nglob + j * 16, gate_r[r] * v[r]);
            }
        }
    }
}

// ---------------------------------------------------------------------- launch
extern "C" void kernel_launch(void* const* d_in, const int* in_sizes, int n_in,
                              void* d_out, int out_size, void* d_ws, size_t ws_size,
                              hipStream_t stream) {
    (void)in_sizes; (void)n_in; (void)out_size; (void)ws_size;
    const float* x    = (const float*)d_in[0];
    const float* rw   = (const float*)d_in[1];
    const float* w1   = (const float*)d_in[2];
    const float* w2   = (const float*)d_in[3];
    const float* bias = (const float*)d_in[4];
    float* out = (float*)d_out;

    char* p = (char*)d_ws;
    unsigned short* w1t  = (unsigned short*)p; p += (size_t)NE * FFN * HS * 2;
    unsigned short* w2t  = (unsigned short*)p; p += (size_t)NE * HS * FFN * 2;
    unsigned short* xb   = (unsigned short*)p; p += (size_t)TOKENS * HS * 2;
    unsigned short* hbuf = (unsigned short*)p; p += (size_t)NE * 1024 * FFN * 2;
    int*   topk_e    = (int*)p;   p += (size_t)TOKENS * 2 * 4;
    float* topk_w    = (float*)p; p += (size_t)TOKENS * 2 * 4;
    int*   comb_tok  = (int*)p;   p += (size_t)NE * 1024 * 4;
    float* comb_gate = (float*)p; p += (size_t)NE * 1024 * 4;

    cvt_x_kernel<<<2048, 256, 0, stream>>>(x, xb);
    transpose_cvt_kernel<<<dim3(FFN / 64, HS / 64, NE), 256, 0, stream>>>(w1, w1t, HS, FFN);
    transpose_cvt_kernel<<<dim3(HS / 64, FFN / 64, NE), 256, 0, stream>>>(w2, w2t, FFN, HS);
    router_kernel<<<TOKENS / 4, 256, 0, stream>>>(x, rw, topk_e, topk_w);
    dispatch_kernel<<<1, 1024, 0, stream>>>(topk_e, topk_w, comb_tok, comb_gate);
    init_out_kernel<<<4096, 256, 0, stream>>>(out, bias);
    gemm1_kernel<<<2048, 256, 0, stream>>>(xb, w1t, comb_tok, hbuf);
    gemm2_kernel<<<1024, 256, 0, stream>>>(hbuf, w2t, comb_tok, comb_gate, out);
}

// Round 3
// 637.172 us; speedup vs baseline: 1.0196x; 1.0196x over previous
//
#include <hip/hip_runtime.h>
#include <stdint.h>

#define TOKENS 4096
#define HS 1024
#define FFN 4096
#define NE 8
#define CAP 512

typedef __attribute__((ext_vector_type(8))) __bf16 v8bf;
typedef __attribute__((ext_vector_type(4))) float v4f;
typedef __attribute__((ext_vector_type(8))) unsigned short v8us;

typedef __attribute__((address_space(1))) void AS1void;
typedef __attribute__((address_space(1))) const void AS1cvoid;
typedef __attribute__((address_space(3))) void AS3void;

// round-to-nearest-even fp32 -> bf16 bits
__device__ __forceinline__ unsigned short f2bf(float f) {
    union { float f; unsigned int u; } c; c.f = f;
    unsigned int u = c.u;
    unsigned int r = (u + 0x7fffu + ((u >> 16) & 1u)) >> 16;
    return (unsigned short)r;
}

// async global->LDS, 16B per lane. LDS dest must be wave-uniform base; HW adds lane*16.
__device__ __forceinline__ void gload16(const void* g, void* l) {
    __builtin_amdgcn_global_load_lds((AS1cvoid*)g, (AS3void*)l, 16, 0, 0);
}

// exact tanh via hardware exp: tanh(u) = sign(u) * (1 - e^{-2|u|}) / (1 + e^{-2|u|})
__device__ __forceinline__ float fast_tanh(float u) {
    float a = __expf(-2.f * fabsf(u));
    float t = (1.f - a) / (1.f + a);
    return copysignf(t, u);
}

// ---------------------------------------------------------------- cvt x -> bf16
__global__ void cvt_x_kernel(const float* __restrict__ x, unsigned short* __restrict__ xb) {
    size_t i = (size_t)blockIdx.x * 256 + threadIdx.x;   // 524288 threads, 8 floats each
    const float4* xv = (const float4*)x;
    float4 a = xv[i * 2];
    float4 b = xv[i * 2 + 1];
    v8us r;
    r[0] = f2bf(a.x); r[1] = f2bf(a.y); r[2] = f2bf(a.z); r[3] = f2bf(a.w);
    r[4] = f2bf(b.x); r[5] = f2bf(b.y); r[6] = f2bf(b.z); r[7] = f2bf(b.w);
    *(v8us*)(xb + i * 8) = r;
}

// ------------------------------------------- transpose + convert weights -> bf16
// in: [E][rows][cols] fp32 -> out: [E][cols][rows] bf16.  64x64 tiles, block=256.
__global__ void transpose_cvt_kernel(const float* __restrict__ in,
                                     unsigned short* __restrict__ outp,
                                     int rows, int cols) {
    __shared__ float tile[64][65];
    const size_t esz = (size_t)rows * cols;
    const float* ine = in + (size_t)blockIdx.z * esz;
    unsigned short* oute = outp + (size_t)blockIdx.z * esz;
    int c0 = blockIdx.x * 64, r0 = blockIdx.y * 64;
    int t = threadIdx.x;
    int lc = (t & 15) * 4;      // col offset in tile (float4)
    int lr = t >> 4;            // 0..15
#pragma unroll
    for (int i = 0; i < 4; ++i) {
        int r = lr + 16 * i;
        float4 v = *(const float4*)&ine[(size_t)(r0 + r) * cols + c0 + lc];
        tile[r][lc] = v.x; tile[r][lc + 1] = v.y; tile[r][lc + 2] = v.z; tile[r][lc + 3] = v.w;
    }
    __syncthreads();
    int oc = t >> 2;            // 0..63 output row (= input col)
    int rc = (t & 3) * 8;       // row chunk base
#pragma unroll
    for (int i = 0; i < 2; ++i) {
        int rb = rc + 32 * i;
        v8us v;
#pragma unroll
        for (int j = 0; j < 8; ++j) v[j] = f2bf(tile[rb + j][oc]);
        *(v8us*)&oute[(size_t)(c0 + oc) * rows + r0 + rb] = v;
    }
}

// ---------------------------------------------------------------- router top-2
__global__ void router_kernel(const float* __restrict__ x, const float* __restrict__ rw,
                              int* __restrict__ topk_e, float* __restrict__ topk_w) {
    __shared__ float rwT[NE * HS];   // rwT[e][hs]
    int tid = threadIdx.x;           // 256
    for (int i = tid; i < NE * HS; i += 256)
        rwT[(i & 7) * HS + (i >> 3)] = rw[i];
    __syncthreads();
    int lane = tid & 63, wave = tid >> 6;
    int t = blockIdx.x * 4 + wave;
    const float* xr = x + (size_t)t * HS;
    float acc[NE] = {0.f, 0.f, 0.f, 0.f, 0.f, 0.f, 0.f, 0.f};
#pragma unroll
    for (int it = 0; it < 16; ++it) {
        float xv = xr[lane + 64 * it];
#pragma unroll
        for (int e = 0; e < NE; ++e) acc[e] += xv * rwT[e * HS + lane + 64 * it];
    }
#pragma unroll
    for (int e = 0; e < NE; ++e) {
#pragma unroll
        for (int off = 32; off > 0; off >>= 1)
            acc[e] += __shfl_down(acc[e], off, 64);
    }
    if (lane == 0) {
        int b1 = 0; float v1 = acc[0];
#pragma unroll
        for (int e = 1; e < NE; ++e) if (acc[e] > v1) { v1 = acc[e]; b1 = e; }
        int b2 = -1; float v2 = -3.4e38f;
#pragma unroll
        for (int e = 0; e < NE; ++e)
            if (e != b1 && acc[e] > v2) { v2 = acc[e]; b2 = e; }
        float s = 0.f;
#pragma unroll
        for (int e = 0; e < NE; ++e) s += expf(acc[e] - v1);
        float inv = 1.f / s;
        topk_e[t * 2] = b1;
        topk_e[t * 2 + 1] = b2;
        topk_w[t * 2] = inv;                 // exp(v1-v1)/s
        topk_w[t * 2 + 1] = expf(v2 - v1) * inv;
    }
}

// ------------------------------------------------- dispatch: stable capped lists
// per-expert combined lists [k=0 kept][k=1 kept]; also slot_of[t][k] (-1 = dropped)
__global__ void dispatch_kernel(const int* __restrict__ topk_e,
                                const float* __restrict__ topk_w,
                                int* __restrict__ comb_tok,
                                float* __restrict__ comb_gate,
                                int* __restrict__ slot_of) {
    __shared__ int hist[1024 * 8];
    __shared__ int c0[NE];
    __shared__ int tpe_s[NE];
    const int tid = threadIdx.x;   // 1024
    for (int i = tid; i < NE * 1024; i += 1024) { comb_tok[i] = 0; comb_gate[i] = 0.f; }

    for (int k = 0; k < 2; ++k) {
        int cnt[NE];
#pragma unroll
        for (int e = 0; e < NE; ++e) cnt[e] = 0;
        int myexp[4];
#pragma unroll
        for (int j = 0; j < 4; ++j) {
            int t = tid * 4 + j;
            int ex = topk_e[t * 2 + k];
            myexp[j] = ex;
            cnt[ex]++;
        }
#pragma unroll
        for (int e = 0; e < NE; ++e) hist[tid * 8 + e] = cnt[e];
        __syncthreads();
        for (int off = 1; off < 1024; off <<= 1) {
            int v[NE];
#pragma unroll
            for (int e = 0; e < NE; ++e) {
                v[e] = hist[tid * 8 + e];
                if (tid >= off) v[e] += hist[(tid - off) * 8 + e];
            }
            __syncthreads();
#pragma unroll
            for (int e = 0; e < NE; ++e) hist[tid * 8 + e] = v[e];
            __syncthreads();
        }
        int base[NE];
#pragma unroll
        for (int e = 0; e < NE; ++e) base[e] = hist[tid * 8 + e] - cnt[e];
        if (tid == 1023) {
#pragma unroll
            for (int e = 0; e < NE; ++e) tpe_s[e] = hist[1023 * 8 + e];
        }
        __syncthreads();
        if (k == 0 && tid < NE) c0[tid] = min(tpe_s[tid], CAP);
        __syncthreads();
#pragma unroll
        for (int j = 0; j < 4; ++j) {
            int t = tid * 4 + j;
            int ex = myexp[j];
            int p = base[ex]++;
            int sl = -1;
            if (p < CAP) {
                int idx = (k == 0) ? p : (c0[ex] + p);
                sl = ex * 1024 + idx;
                comb_tok[sl] = t;
                comb_gate[sl] = topk_w[t * 2 + k];
            }
            slot_of[t * 2 + k] = sl;
        }
        __syncthreads();
    }
}

// ------------------------------------------------- GEMM1: h = gelu(gather(x) @ W1e)
// 1D grid 2048: id&7 = expert (XCD-affine), rest: mt 0..7, nt 0..31. Double-buffered LDS.
__global__ __launch_bounds__(256) void gemm1_kernel(
    const unsigned short* __restrict__ xb,      // [TOKENS][HS] bf16
    const unsigned short* __restrict__ w1t,     // [E][FFN][HS] bf16 (pre-transposed)
    const int* __restrict__ comb_tok,           // [E][1024]
    unsigned short* __restrict__ h)             // [E][1024][FFN] bf16
{
    __shared__ __align__(16) unsigned short As[2][128 * 32];
    __shared__ __align__(16) unsigned short Bs[2][128 * 32];
    const int id = blockIdx.x;
    const int e = id & 7;
    const int rest = id >> 3;
    const int mt = rest & 7;
    const int nt = rest >> 3;     // 0..31
    const int tid = threadIdx.x;
    const int lane = tid & 63;
    const int wave = tid >> 6;
    const int seg = lane & 3;
    const int lrow = lane >> 2;

    const int arow0 = wave * 32 + lrow;
    const int arow1 = arow0 + 16;
    const int tok0 = comb_tok[e * 1024 + mt * 128 + arow0];
    const int tok1 = comb_tok[e * 1024 + mt * 128 + arow1];
    const unsigned short* gA0 = xb + (size_t)tok0 * HS + seg * 8;
    const unsigned short* gA1 = xb + (size_t)tok1 * HS + seg * 8;
    const unsigned short* wb = w1t + (size_t)e * FFN * HS;
    const unsigned short* gB0 = wb + (size_t)(nt * 128 + arow0) * HS + seg * 8;
    const unsigned short* gB1 = wb + (size_t)(nt * 128 + arow1) * HS + seg * 8;

    const int m = lane & 15;
    const int quad = lane >> 4;
    const int wr = wave >> 1;
    const int wc = wave & 1;

    v4f acc[4][4];
#pragma unroll
    for (int i = 0; i < 4; ++i)
#pragma unroll
        for (int j = 0; j < 4; ++j) acc[i][j] = (v4f)(0.f);

    auto stage = [&](int buf, int k0) {
        gload16(gA0 + k0, &As[buf][wave * 1024]);
        gload16(gA1 + k0, &As[buf][wave * 1024 + 512]);
        gload16(gB0 + k0, &Bs[buf][wave * 1024]);
        gload16(gB1 + k0, &Bs[buf][wave * 1024 + 512]);
    };

    const int NK = HS / 32;
    stage(0, 0);
    for (int kt = 0; kt < NK; ++kt) {
        const int cur = kt & 1;
        __syncthreads();                       // drains this buf's prefetch
        if (kt + 1 < NK) stage(cur ^ 1, (kt + 1) * 32);   // in flight during compute
        v8bf a[4], b[4];
#pragma unroll
        for (int i = 0; i < 4; ++i)
            a[i] = *(const v8bf*)&As[cur][(wr * 64 + i * 16 + m) * 32 + quad * 8];
#pragma unroll
        for (int j = 0; j < 4; ++j)
            b[j] = *(const v8bf*)&Bs[cur][(wc * 64 + j * 16 + m) * 32 + quad * 8];
#pragma unroll
        for (int i = 0; i < 4; ++i)
#pragma unroll
            for (int j = 0; j < 4; ++j)
                acc[i][j] = __builtin_amdgcn_mfma_f32_16x16x32_bf16(a[i], b[j], acc[i][j], 0, 0, 0);
    }

    unsigned short* hb = h + (size_t)e * 1024 * FFN;
    const int mbase = mt * 128 + wr * 64;
    const int nbase = nt * 128 + wc * 64 + m;
#pragma unroll
    for (int i = 0; i < 4; ++i) {
#pragma unroll
        for (int j = 0; j < 4; ++j) {
            v4f v = acc[i][j];
#pragma unroll
            for (int r = 0; r < 4; ++r) {
                int row = mbase + i * 16 + quad * 4 + r;
                int col = nbase + j * 16;
                float val = v[r];
                float inner = 0.7978845608028654f * (val + 0.044715f * val * val * val);
                float g = 0.5f * val * (1.f + fast_tanh(inner));
                hb[(size_t)row * FFN + col] = f2bf(g);
            }
        }
    }
}

// ------------------------------------------------- GEMM2: y[slot] = gate * (h @ W2e)
// 1D grid 512: id&7 = expert (XCD-affine); rest: mt 0..7, nt 0..7. Double-buffered LDS.
__global__ __launch_bounds__(256) void gemm2_kernel(
    const unsigned short* __restrict__ h,       // [E][1024][FFN] bf16
    const unsigned short* __restrict__ w2t,     // [E][HS][FFN] bf16 (pre-transposed)
    const float* __restrict__ comb_gate,
    float* __restrict__ y)                      // [E*1024][HS] fp32
{
    __shared__ __align__(16) unsigned short As[2][128 * 32];
    __shared__ __align__(16) unsigned short Bs[2][128 * 32];
    const int id = blockIdx.x;
    const int e = id & 7;
    const int rest = id >> 3;
    const int mt = rest & 7;
    const int nt = rest >> 3;
    const int tid = threadIdx.x;
    const int lane = tid & 63;
    const int wave = tid >> 6;
    const int seg = lane & 3;
    const int lrow = lane >> 2;

    const int arow0 = wave * 32 + lrow;
    const int arow1 = arow0 + 16;
    const unsigned short* hb = h + (size_t)e * 1024 * FFN;
    const unsigned short* gA0 = hb + (size_t)(mt * 128 + arow0) * FFN + seg * 8;
    const unsigned short* gA1 = hb + (size_t)(mt * 128 + arow1) * FFN + seg * 8;
    const unsigned short* wb = w2t + (size_t)e * HS * FFN;
    const unsigned short* gB0 = wb + (size_t)(nt * 128 + arow0) * FFN + seg * 8;
    const unsigned short* gB1 = wb + (size_t)(nt * 128 + arow1) * FFN + seg * 8;

    const int m = lane & 15;
    const int quad = lane >> 4;
    const int wr = wave >> 1;
    const int wc = wave & 1;

    v4f acc[4][4];
#pragma unroll
    for (int i = 0; i < 4; ++i)
#pragma unroll
        for (int j = 0; j < 4; ++j) acc[i][j] = (v4f)(0.f);

    auto stage = [&](int buf, int k0) {
        gload16(gA0 + k0, &As[buf][wave * 1024]);
        gload16(gA1 + k0, &As[buf][wave * 1024 + 512]);
        gload16(gB0 + k0, &Bs[buf][wave * 1024]);
        gload16(gB1 + k0, &Bs[buf][wave * 1024 + 512]);
    };

    const int NK = FFN / 32;
    stage(0, 0);
    for (int kt = 0; kt < NK; ++kt) {
        const int cur = kt & 1;
        __syncthreads();
        if (kt + 1 < NK) stage(cur ^ 1, (kt + 1) * 32);
        v8bf a[4], b[4];
#pragma unroll
        for (int i = 0; i < 4; ++i)
            a[i] = *(const v8bf*)&As[cur][(wr * 64 + i * 16 + m) * 32 + quad * 8];
#pragma unroll
        for (int j = 0; j < 4; ++j)
            b[j] = *(const v8bf*)&Bs[cur][(wc * 64 + j * 16 + m) * 32 + quad * 8];
#pragma unroll
        for (int i = 0; i < 4; ++i)
#pragma unroll
            for (int j = 0; j < 4; ++j)
                acc[i][j] = __builtin_amdgcn_mfma_f32_16x16x32_bf16(a[i], b[j], acc[i][j], 0, 0, 0);
    }

    float* yb = y + (size_t)e * 1024 * HS;
    const int mbase = mt * 128 + wr * 64;
    const int nglob = nt * 128 + wc * 64 + m;
#pragma unroll
    for (int i = 0; i < 4; ++i) {
        float gate_r[4];
        int row_r[4];
#pragma unroll
        for (int r = 0; r < 4; ++r) {
            row_r[r] = mbase + i * 16 + quad * 4 + r;
            gate_r[r] = comb_gate[e * 1024 + row_r[r]];
        }
#pragma unroll
        for (int j = 0; j < 4; ++j) {
            v4f v = acc[i][j];
#pragma unroll
            for (int r = 0; r < 4; ++r)
                yb[(size_t)row_r[r] * HS + nglob + j * 16] = gate_r[r] * v[r];
        }
    }
}

// ------------------------------------------------- combine: out = bias + y[s0] + y[s1]
__global__ void combine_kernel(const float* __restrict__ y,
                               const int* __restrict__ slot_of,
                               const float* __restrict__ bias,
                               float* __restrict__ out) {
    int i = blockIdx.x * 256 + threadIdx.x;    // float4 index, 1M total
    int t = i >> 8;
    int c = i & 255;
    const float4* y4 = (const float4*)y;
    float4 a = ((const float4*)bias)[c];
    int s0 = slot_of[t * 2];
    int s1 = slot_of[t * 2 + 1];
    if (s0 >= 0) {
        float4 v = y4[(size_t)s0 * 256 + c];
        a.x += v.x; a.y += v.y; a.z += v.z; a.w += v.w;
    }
    if (s1 >= 0) {
        float4 v = y4[(size_t)s1 * 256 + c];
        a.x += v.x; a.y += v.y; a.z += v.z; a.w += v.w;
    }
    ((float4*)out)[i] = a;
}

// ---------------------------------------------------------------------- launch
extern "C" void kernel_launch(void* const* d_in, const int* in_sizes, int n_in,
                              void* d_out, int out_size, void* d_ws, size_t ws_size,
                              hipStream_t stream) {
    (void)in_sizes; (void)n_in; (void)out_size; (void)ws_size;
    const float* x    = (const float*)d_in[0];
    const float* rw   = (const float*)d_in[1];
    const float* w1   = (const float*)d_in[2];
    const float* w2   = (const float*)d_in[3];
    const float* bias = (const float*)d_in[4];
    float* out = (float*)d_out;

    char* p = (char*)d_ws;
    unsigned short* w1t  = (unsigned short*)p; p += (size_t)NE * FFN * HS * 2;
    unsigned short* w2t  = (unsigned short*)p; p += (size_t)NE * HS * FFN * 2;
    unsigned short* xb   = (unsigned short*)p; p += (size_t)TOKENS * HS * 2;
    unsigned short* hbuf = (unsigned short*)p; p += (size_t)NE * 1024 * FFN * 2;
    float* ybuf      = (float*)p; p += (size_t)NE * 1024 * HS * 4;
    int*   topk_e    = (int*)p;   p += (size_t)TOKENS * 2 * 4;
    float* topk_w    = (float*)p; p += (size_t)TOKENS * 2 * 4;
    int*   comb_tok  = (int*)p;   p += (size_t)NE * 1024 * 4;
    float* comb_gate = (float*)p; p += (size_t)NE * 1024 * 4;
    int*   slot_of   = (int*)p;   p += (size_t)TOKENS * 2 * 4;

    cvt_x_kernel<<<2048, 256, 0, stream>>>(x, xb);
    transpose_cvt_kernel<<<dim3(FFN / 64, HS / 64, NE), 256, 0, stream>>>(w1, w1t, HS, FFN);
    transpose_cvt_kernel<<<dim3(HS / 64, FFN / 64, NE), 256, 0, stream>>>(w2, w2t, FFN, HS);
    router_kernel<<<TOKENS / 4, 256, 0, stream>>>(x, rw, topk_e, topk_w);
    dispatch_kernel<<<1, 1024, 0, stream>>>(topk_e, topk_w, comb_tok, comb_gate, slot_of);
    gemm1_kernel<<<2048, 256, 0, stream>>>(xb, w1t, comb_tok, hbuf);
    gemm2_kernel<<<512, 256, 0, stream>>>(hbuf, w2t, comb_gate, ybuf);
    combine_kernel<<<4096, 256, 0, stream>>>(ybuf, slot_of, bias, out);
}

// Round 4
// 620.450 us; speedup vs baseline: 1.0471x; 1.0270x over previous
//
#include <hip/hip_runtime.h>
#include <stdint.h>

#define TOKENS 4096
#define HS 1024
#define FFN 4096
#define NE 8
#define CAP 512

typedef __attribute__((ext_vector_type(8))) __bf16 v8bf;
typedef __attribute__((ext_vector_type(4))) float v4f;
typedef __attribute__((ext_vector_type(8))) unsigned short v8us;
typedef __attribute__((ext_vector_type(4))) unsigned short v4us;

typedef __attribute__((address_space(1))) const void AS1cvoid;
typedef __attribute__((address_space(3))) void AS3void;

// round-to-nearest-even fp32 -> bf16 bits
__device__ __forceinline__ unsigned short f2bf(float f) {
    union { float f; unsigned int u; } c; c.f = f;
    unsigned int u = c.u;
    unsigned int r = (u + 0x7fffu + ((u >> 16) & 1u)) >> 16;
    return (unsigned short)r;
}

// async global->LDS, 16B per lane. LDS dest must be wave-uniform base; HW adds lane*16.
__device__ __forceinline__ void gload16(const void* g, void* l) {
    __builtin_amdgcn_global_load_lds((AS1cvoid*)g, (AS3void*)l, 16, 0, 0);
}

// ------------------------------- fused transpose+cvt for both weights, one launch
// w1: [E][HS][FFN] -> w1t [E][FFN][HS]; w2: [E][FFN][HS] -> w2t [E][HS][FFN]
__global__ void transpose_cvt2_kernel(const float* __restrict__ w1, unsigned short* __restrict__ w1t,
                                      const float* __restrict__ w2, unsigned short* __restrict__ w2t) {
    __shared__ float tile[64][65];
    const int id = blockIdx.x;           // 16384
    const int half = id >> 13;           // 0: w1, 1: w2
    const int e = id & 7;
    const int rest = (id >> 3) & 1023;
    int rows, cols, rt, ct;
    const float* inp;
    unsigned short* outp;
    if (half == 0) { rows = HS; cols = FFN; rt = rest & 15; ct = rest >> 4; inp = w1; outp = w1t; }
    else           { rows = FFN; cols = HS; rt = rest >> 4; ct = rest & 15; inp = w2; outp = w2t; }
    const size_t esz = (size_t)rows * cols;
    const float* ine = inp + (size_t)e * esz;
    unsigned short* oute = outp + (size_t)e * esz;
    int c0 = ct * 64, r0 = rt * 64;
    int t = threadIdx.x;
    int lc = (t & 15) * 4;
    int lr = t >> 4;
#pragma unroll
    for (int i = 0; i < 4; ++i) {
        int r = lr + 16 * i;
        float4 v = *(const float4*)&ine[(size_t)(r0 + r) * cols + c0 + lc];
        tile[r][lc] = v.x; tile[r][lc + 1] = v.y; tile[r][lc + 2] = v.z; tile[r][lc + 3] = v.w;
    }
    __syncthreads();
    int oc = t >> 2;
    int rc = (t & 3) * 8;
#pragma unroll
    for (int i = 0; i < 2; ++i) {
        int rb = rc + 32 * i;
        v8us v;
#pragma unroll
        for (int j = 0; j < 8; ++j) v[j] = f2bf(tile[rb + j][oc]);
        *(v8us*)&oute[(size_t)(c0 + oc) * rows + r0 + rb] = v;
    }
}

// --------------------------- fused router top-2 + x->bf16 conversion (x read once)
__global__ void router_kernel(const float* __restrict__ x, const float* __restrict__ rw,
                              unsigned short* __restrict__ xb,
                              int* __restrict__ topk_e, float* __restrict__ topk_w) {
    __shared__ float rwT[NE * HS];   // rwT[e][hs]
    int tid = threadIdx.x;           // 256
    for (int i = tid; i < NE * HS; i += 256)
        rwT[(i & 7) * HS + (i >> 3)] = rw[i];
    __syncthreads();
    int lane = tid & 63, wave = tid >> 6;
    int t = blockIdx.x * 4 + wave;
    const float4* xr4 = (const float4*)(x + (size_t)t * HS);
    unsigned short* xbr = xb + (size_t)t * HS;
    float acc[NE] = {0.f, 0.f, 0.f, 0.f, 0.f, 0.f, 0.f, 0.f};
#pragma unroll
    for (int it = 0; it < 4; ++it) {
        float4 f = xr4[it * 64 + lane];
        int h0 = (it * 64 + lane) * 4;
#pragma unroll
        for (int e = 0; e < NE; ++e) {
            float4 rv = *(const float4*)&rwT[e * HS + h0];
            acc[e] += f.x * rv.x + f.y * rv.y + f.z * rv.z + f.w * rv.w;
        }
        v4us p;
        p[0] = f2bf(f.x); p[1] = f2bf(f.y); p[2] = f2bf(f.z); p[3] = f2bf(f.w);
        *(v4us*)&xbr[h0] = p;
    }
#pragma unroll
    for (int e = 0; e < NE; ++e) {
#pragma unroll
        for (int off = 32; off > 0; off >>= 1)
            acc[e] += __shfl_down(acc[e], off, 64);
    }
    if (lane == 0) {
        int b1 = 0; float v1 = acc[0];
#pragma unroll
        for (int e = 1; e < NE; ++e) if (acc[e] > v1) { v1 = acc[e]; b1 = e; }
        int b2 = -1; float v2 = -3.4e38f;
#pragma unroll
        for (int e = 0; e < NE; ++e)
            if (e != b1 && acc[e] > v2) { v2 = acc[e]; b2 = e; }
        float s = 0.f;
#pragma unroll
        for (int e = 0; e < NE; ++e) s += expf(acc[e] - v1);
        float inv = 1.f / s;
        topk_e[t * 2] = b1;
        topk_e[t * 2 + 1] = b2;
        topk_w[t * 2] = inv;
        topk_w[t * 2 + 1] = expf(v2 - v1) * inv;
    }
}

// ------------------------------------------------- dispatch: stable capped lists
__global__ void dispatch_kernel(const int* __restrict__ topk_e,
                                const float* __restrict__ topk_w,
                                int* __restrict__ comb_tok,
                                float* __restrict__ comb_gate,
                                int* __restrict__ slot_of) {
    __shared__ int hist[1024 * 8];
    __shared__ int c0[NE];
    __shared__ int tpe_s[NE];
    const int tid = threadIdx.x;   // 1024
    for (int i = tid; i < NE * 1024; i += 1024) { comb_tok[i] = 0; comb_gate[i] = 0.f; }

    for (int k = 0; k < 2; ++k) {
        int cnt[NE];
#pragma unroll
        for (int e = 0; e < NE; ++e) cnt[e] = 0;
        int myexp[4];
#pragma unroll
        for (int j = 0; j < 4; ++j) {
            int t = tid * 4 + j;
            int ex = topk_e[t * 2 + k];
            myexp[j] = ex;
            cnt[ex]++;
        }
#pragma unroll
        for (int e = 0; e < NE; ++e) hist[tid * 8 + e] = cnt[e];
        __syncthreads();
        for (int off = 1; off < 1024; off <<= 1) {
            int v[NE];
#pragma unroll
            for (int e = 0; e < NE; ++e) {
                v[e] = hist[tid * 8 + e];
                if (tid >= off) v[e] += hist[(tid - off) * 8 + e];
            }
            __syncthreads();
#pragma unroll
            for (int e = 0; e < NE; ++e) hist[tid * 8 + e] = v[e];
            __syncthreads();
        }
        int base[NE];
#pragma unroll
        for (int e = 0; e < NE; ++e) base[e] = hist[tid * 8 + e] - cnt[e];
        if (tid == 1023) {
#pragma unroll
            for (int e = 0; e < NE; ++e) tpe_s[e] = hist[1023 * 8 + e];
        }
        __syncthreads();
        if (k == 0 && tid < NE) c0[tid] = min(tpe_s[tid], CAP);
        __syncthreads();
#pragma unroll
        for (int j = 0; j < 4; ++j) {
            int t = tid * 4 + j;
            int ex = myexp[j];
            int p = base[ex]++;
            int sl = -1;
            if (p < CAP) {
                int idx = (k == 0) ? p : (c0[ex] + p);
                sl = ex * 1024 + idx;
                comb_tok[sl] = t;
                comb_gate[sl] = topk_w[t * 2 + k];
            }
            slot_of[t * 2 + k] = sl;
        }
        __syncthreads();
    }
}

// ------------------------------------------------- GEMM1: h = gelu(gather(x) @ W1e)
// grid 2048: id&7 = expert (XCD-affine); rest: mt 0..7, nt 0..31. Dbuf LDS + LDS C-repack.
#define CT_STRIDE 132   // conflict-free epilogue writes; 128*132 ushorts = 33792 B
__global__ __launch_bounds__(256) void gemm1_kernel(
    const unsigned short* __restrict__ xb,      // [TOKENS][HS] bf16
    const unsigned short* __restrict__ w1t,     // [E][FFN][HS] bf16
    const int* __restrict__ comb_tok,           // [E][1024]
    unsigned short* __restrict__ h)             // [E][1024][FFN] bf16
{
    __shared__ __align__(16) unsigned short smem[128 * CT_STRIDE];  // staging (32 KB) then C-tile
    const int id = blockIdx.x;
    const int e = id & 7;
    const int rest = id >> 3;
    const int mt = rest & 7;
    const int nt = rest >> 3;     // 0..31
    const int tid = threadIdx.x;
    const int lane = tid & 63;
    const int wave = tid >> 6;
    const int seg = lane & 3;
    const int lrow = lane >> 2;

    const int arow0 = wave * 32 + lrow;
    const int arow1 = arow0 + 16;
    const int tok0 = comb_tok[e * 1024 + mt * 128 + arow0];
    const int tok1 = comb_tok[e * 1024 + mt * 128 + arow1];
    const unsigned short* gA0 = xb + (size_t)tok0 * HS + seg * 8;
    const unsigned short* gA1 = xb + (size_t)tok1 * HS + seg * 8;
    const unsigned short* wb = w1t + (size_t)e * FFN * HS;
    const unsigned short* gB0 = wb + (size_t)(nt * 128 + arow0) * HS + seg * 8;
    const unsigned short* gB1 = wb + (size_t)(nt * 128 + arow1) * HS + seg * 8;

    const int m = lane & 15;
    const int quad = lane >> 4;
    const int wr = wave >> 1;
    const int wc = wave & 1;

    v4f acc[4][4];
#pragma unroll
    for (int i = 0; i < 4; ++i)
#pragma unroll
        for (int j = 0; j < 4; ++j) acc[i][j] = (v4f)(0.f);

    auto stage = [&](int buf, int k0) {
        unsigned short* A = smem + buf * 4096;
        unsigned short* B = smem + 8192 + buf * 4096;
        gload16(gA0 + k0, A + wave * 1024);
        gload16(gA1 + k0, A + wave * 1024 + 512);
        gload16(gB0 + k0, B + wave * 1024);
        gload16(gB1 + k0, B + wave * 1024 + 512);
    };

    const int NK = HS / 32;
    stage(0, 0);
    for (int kt = 0; kt < NK; ++kt) {
        const int cur = kt & 1;
        __syncthreads();
        if (kt + 1 < NK) stage(cur ^ 1, (kt + 1) * 32);
        const unsigned short* A = smem + cur * 4096;
        const unsigned short* B = smem + 8192 + cur * 4096;
        v8bf a[4], b[4];
#pragma unroll
        for (int i = 0; i < 4; ++i)
            a[i] = *(const v8bf*)&A[(wr * 64 + i * 16 + m) * 32 + quad * 8];
#pragma unroll
        for (int j = 0; j < 4; ++j)
            b[j] = *(const v8bf*)&B[(wc * 64 + j * 16 + m) * 32 + quad * 8];
#pragma unroll
        for (int i = 0; i < 4; ++i)
#pragma unroll
            for (int j = 0; j < 4; ++j)
                acc[i][j] = __builtin_amdgcn_mfma_f32_16x16x32_bf16(a[i], b[j], acc[i][j], 0, 0, 0);
    }

    // epilogue: gelu -> LDS repack -> coalesced 16B stores
    __syncthreads();   // staging reads complete before overwrite
#pragma unroll
    for (int i = 0; i < 4; ++i) {
#pragma unroll
        for (int j = 0; j < 4; ++j) {
            v4f v = acc[i][j];
#pragma unroll
            for (int r = 0; r < 4; ++r) {
                int rl = wr * 64 + i * 16 + quad * 4 + r;
                int cl = wc * 64 + j * 16 + m;
                float val = v[r];
                float inner = 0.7978845608028654f * (val + 0.044715f * val * val * val);
                // exact: 0.5*val*(1+tanh(inner)) == val * sigmoid(2*inner)
                float g = val / (1.f + __expf(-2.f * inner));
                smem[rl * CT_STRIDE + cl] = f2bf(g);
            }
        }
    }
    __syncthreads();
    unsigned short* hb = h + (size_t)e * 1024 * FFN + (size_t)(mt * 128) * FFN + nt * 128;
    const int srow = tid >> 4;        // 0..15
    const int scol = (tid & 15) * 8;  // 0..120
#pragma unroll
    for (int pass = 0; pass < 8; ++pass) {
        int row = pass * 16 + srow;
        v4us lo = *(const v4us*)&smem[row * CT_STRIDE + scol];
        v4us hi = *(const v4us*)&smem[row * CT_STRIDE + scol + 4];
        v8us v;
        v[0] = lo[0]; v[1] = lo[1]; v[2] = lo[2]; v[3] = lo[3];
        v[4] = hi[0]; v[5] = hi[1]; v[6] = hi[2]; v[7] = hi[3];
        *(v8us*)&hb[(size_t)row * FFN + scol] = v;
    }
}

// ------------------------------------------------- GEMM2: y_ks[slot] = gate * (h @ W2e)_Khalf
// grid 1024: id&7 = expert (XCD-affine); rest: mt 0..7, nt 0..7, ks 0..1 (split-K, plain stores)
__global__ __launch_bounds__(256) void gemm2_kernel(
    const unsigned short* __restrict__ h,       // [E][1024][FFN] bf16
    const unsigned short* __restrict__ w2t,     // [E][HS][FFN] bf16
    const float* __restrict__ comb_gate,
    float* __restrict__ y0,                     // [E*1024][HS] fp32 (K half 0)
    float* __restrict__ y1)                     // [E*1024][HS] fp32 (K half 1)
{
    __shared__ __align__(16) unsigned short As[2][128 * 32];
    __shared__ __align__(16) unsigned short Bs[2][128 * 32];
    const int id = blockIdx.x;
    const int e = id & 7;
    const int rest = id >> 3;
    const int mt = rest & 7;
    const int nt = (rest >> 3) & 7;
    const int ks = rest >> 6;
    const int tid = threadIdx.x;
    const int lane = tid & 63;
    const int wave = tid >> 6;
    const int seg = lane & 3;
    const int lrow = lane >> 2;

    const int arow0 = wave * 32 + lrow;
    const int arow1 = arow0 + 16;
    const unsigned short* hb = h + (size_t)e * 1024 * FFN;
    const unsigned short* gA0 = hb + (size_t)(mt * 128 + arow0) * FFN + seg * 8;
    const unsigned short* gA1 = hb + (size_t)(mt * 128 + arow1) * FFN + seg * 8;
    const unsigned short* wb = w2t + (size_t)e * HS * FFN;
    const unsigned short* gB0 = wb + (size_t)(nt * 128 + arow0) * FFN + seg * 8;
    const unsigned short* gB1 = wb + (size_t)(nt * 128 + arow1) * FFN + seg * 8;

    const int m = lane & 15;
    const int quad = lane >> 4;
    const int wr = wave >> 1;
    const int wc = wave & 1;

    v4f acc[4][4];
#pragma unroll
    for (int i = 0; i < 4; ++i)
#pragma unroll
        for (int j = 0; j < 4; ++j) acc[i][j] = (v4f)(0.f);

    auto stage = [&](int buf, int k0) {
        gload16(gA0 + k0, &As[buf][wave * 1024]);
        gload16(gA1 + k0, &As[buf][wave * 1024 + 512]);
        gload16(gB0 + k0, &Bs[buf][wave * 1024]);
        gload16(gB1 + k0, &Bs[buf][wave * 1024 + 512]);
    };

    const int NK = FFN / 64;          // 64 iters per K-half
    const int kt0 = ks * NK;
    stage(0, kt0 * 32);
    for (int it = 0; it < NK; ++it) {
        const int cur = it & 1;
        __syncthreads();
        if (it + 1 < NK) stage(cur ^ 1, (kt0 + it + 1) * 32);
        v8bf a[4], b[4];
#pragma unroll
        for (int i = 0; i < 4; ++i)
            a[i] = *(const v8bf*)&As[cur][(wr * 64 + i * 16 + m) * 32 + quad * 8];
#pragma unroll
        for (int j = 0; j < 4; ++j)
            b[j] = *(const v8bf*)&Bs[cur][(wc * 64 + j * 16 + m) * 32 + quad * 8];
#pragma unroll
        for (int i = 0; i < 4; ++i)
#pragma unroll
            for (int j = 0; j < 4; ++j)
                acc[i][j] = __builtin_amdgcn_mfma_f32_16x16x32_bf16(a[i], b[j], acc[i][j], 0, 0, 0);
    }

    float* yb = (ks ? y1 : y0) + (size_t)e * 1024 * HS;
    const int mbase = mt * 128 + wr * 64;
    const int nglob = nt * 128 + wc * 64 + m;
#pragma unroll
    for (int i = 0; i < 4; ++i) {
        float gate_r[4];
        int row_r[4];
#pragma unroll
        for (int r = 0; r < 4; ++r) {
            row_r[r] = mbase + i * 16 + quad * 4 + r;
            gate_r[r] = comb_gate[e * 1024 + row_r[r]];
        }
#pragma unroll
        for (int j = 0; j < 4; ++j) {
            v4f v = acc[i][j];
#pragma unroll
            for (int r = 0; r < 4; ++r)
                yb[(size_t)row_r[r] * HS + nglob + j * 16] = gate_r[r] * v[r];
        }
    }
}

// --------------------------- combine: out = bias + sum over k,ks of y_ks[slot_k]
__global__ void combine_kernel(const float* __restrict__ y0, const float* __restrict__ y1,
                               const int* __restrict__ slot_of,
                               const float* __restrict__ bias,
                               float* __restrict__ out) {
    int t = blockIdx.x;            // token
    int c = threadIdx.x;           // float4 lane, 256
    const float4* y04 = (const float4*)y0;
    const float4* y14 = (const float4*)y1;
    float4 a = ((const float4*)bias)[c];
    int s0 = slot_of[t * 2];
    int s1 = slot_of[t * 2 + 1];
    if (s0 >= 0) {
        float4 u = y04[(size_t)s0 * 256 + c];
        float4 v = y14[(size_t)s0 * 256 + c];
        a.x += u.x + v.x; a.y += u.y + v.y; a.z += u.z + v.z; a.w += u.w + v.w;
    }
    if (s1 >= 0) {
        float4 u = y04[(size_t)s1 * 256 + c];
        float4 v = y14[(size_t)s1 * 256 + c];
        a.x += u.x + v.x; a.y += u.y + v.y; a.z += u.z + v.z; a.w += u.w + v.w;
    }
    ((float4*)out)[(size_t)t * 256 + c] = a;
}

// ---------------------------------------------------------------------- launch
extern "C" void kernel_launch(void* const* d_in, const int* in_sizes, int n_in,
                              void* d_out, int out_size, void* d_ws, size_t ws_size,
                              hipStream_t stream) {
    (void)in_sizes; (void)n_in; (void)out_size; (void)ws_size;
    const float* x    = (const float*)d_in[0];
    const float* rw   = (const float*)d_in[1];
    const float* w1   = (const float*)d_in[2];
    const float* w2   = (const float*)d_in[3];
    const float* bias = (const float*)d_in[4];
    float* out = (float*)d_out;

    char* p = (char*)d_ws;
    unsigned short* w1t  = (unsigned short*)p; p += (size_t)NE * FFN * HS * 2;   // 64 MB (dead after gemm1)
    unsigned short* w2t  = (unsigned short*)p; p += (size_t)NE * HS * FFN * 2;   // 64 MB
    unsigned short* xb   = (unsigned short*)p; p += (size_t)TOKENS * HS * 2;     // 8 MB
    unsigned short* hbuf = (unsigned short*)p; p += (size_t)NE * 1024 * FFN * 2; // 64 MB
    float* ybuf0     = (float*)p; p += (size_t)NE * 1024 * HS * 4;               // 32 MB
    int*   topk_e    = (int*)p;   p += (size_t)TOKENS * 2 * 4;
    float* topk_w    = (float*)p; p += (size_t)TOKENS * 2 * 4;
    int*   comb_tok  = (int*)p;   p += (size_t)NE * 1024 * 4;
    float* comb_gate = (float*)p; p += (size_t)NE * 1024 * 4;
    int*   slot_of   = (int*)p;   p += (size_t)TOKENS * 2 * 4;
    float* ybuf1 = (float*)w1t;   // alias: w1t dead once gemm1 completes

    transpose_cvt2_kernel<<<16384, 256, 0, stream>>>(w1, w1t, w2, w2t);
    router_kernel<<<TOKENS / 4, 256, 0, stream>>>(x, rw, xb, topk_e, topk_w);
    dispatch_kernel<<<1, 1024, 0, stream>>>(topk_e, topk_w, comb_tok, comb_gate, slot_of);
    gemm1_kernel<<<2048, 256, 0, stream>>>(xb, w1t, comb_tok, hbuf);
    gemm2_kernel<<<1024, 256, 0, stream>>>(hbuf, w2t, comb_gate, ybuf0, ybuf1);
    combine_kernel<<<TOKENS, 256, 0, stream>>>(ybuf0, ybuf1, slot_of, bias, out);
}